// Round 2
// baseline (6086.538 us; speedup 1.0000x reference)
//
#include <hip/hip_runtime.h>
#include <hip/hip_bf16.h>

// FNO spectral layer, B=16, C=64, H=W=256, M=16 modes.
// Pipeline: probe -> k1_dftx -> k2_dfty -> k3_mix -> k4_idfty -> k5_final
// ws: [0,1KB) flag | X1/G1 @1KB (33.5MB) | Cft (4MB) | Outft (4MB)
// Correctness-first round: scalar loads, clamped ws access, dtype-adaptive.

#define TWO_PI 6.283185307179586f
typedef __hip_bfloat16 bf16;

__device__ __forceinline__ float ld_in(const void* p, size_t i, int isf32) {
    if (isf32) return ((const float*)p)[i];
    return __bfloat162float(((const bf16*)p)[i]);
}
__device__ __forceinline__ unsigned clampi(unsigned i, unsigned cap) {
    return i < cap ? i : 0u;
}

// ---- Probe: decide input dtype from raw u16 words of c (safe either way).
__global__ __launch_bounds__(256) void k_probe(const unsigned short* __restrict__ c,
                                               int* __restrict__ flag) {
    __shared__ int cnt;
    if (threadIdx.x == 0) cnt = 0;
    __syncthreads();
    int bad = 0;
    for (int j = 0; j < 4; ++j) {
        unsigned short u = c[threadIdx.x * 4 + j];
        unsigned e = (u >> 7) & 0xFF;
        if (e == 0xFF || e >= 0x87) bad++;   // NaN/Inf or |x| >= 256: impossible for bf16 N(0,1)
    }
    atomicAdd(&cnt, bad);
    __syncthreads();
    if (threadIdx.x == 0) flag[0] = (cnt > 64) ? 1 : 0;   // 1 => inputs are fp32
}

// ---- K1: DFT over x. c[b,i,y,x] -> X1[row= b*64*256-ish][kx], kx=0..15
// block = 16 rows, 256 threads; thread t: row r=t>>4, kx=t&15, full 256-sum.
__global__ __launch_bounds__(256) void k1_dftx(const void* __restrict__ cin,
                                               const int* __restrict__ flag,
                                               float2* __restrict__ X1, unsigned capX1) {
    __shared__ float rows[16][256];
    __shared__ float2 tw[256];
    int t = threadIdx.x;
    int f32 = flag[0];
    float sv, cv;
    sincosf(TWO_PI * (float)t * (1.0f / 256.0f), &sv, &cv);
    tw[t] = make_float2(cv, sv);
    size_t base = (size_t)blockIdx.x * 4096;   // 16 rows * 256
    for (int j = 0; j < 16; ++j)
        rows[j][t] = ld_in(cin, base + j * 256 + t, f32);
    __syncthreads();
    int r = t >> 4, kx = t & 15;
    float re = 0.f, im = 0.f;
    for (int x = 0; x < 256; ++x) {
        float v = rows[r][x];
        float2 w = tw[(kx * x) & 255];          // e^{-i th}: (cos, sin), im -= v*sin
        re = fmaf(v, w.x, re);
        im = fmaf(-v, w.y, im);
    }
    unsigned idx = (blockIdx.x * 16u + r) * 16u + kx;
    X1[clampi(idx, capX1)] = make_float2(re, im);
}

// ---- K2: DFT over y. X1[b,i,y,kx] -> Cft[b,i,kyidx,kx], kyidx 0..31
// kyidx<16 -> ky=kyidx ; kyidx>=16 -> ky=224+kyidx (240..255)
__global__ __launch_bounds__(512) void k2_dfty(const float2* __restrict__ X1,
                                               float2* __restrict__ Cft,
                                               unsigned capX1, unsigned capC) {
    __shared__ float2 tw[256];
    __shared__ float2 xs[4096];  // [y][kx]
    int t = threadIdx.x;
    if (t < 256) {
        float sv, cv;
        sincosf(TWO_PI * (float)t * (1.0f / 256.0f), &sv, &cv);
        tw[t] = make_float2(cv, sv);
    }
    unsigned base = blockIdx.x * 4096u;
    for (int j = 0; j < 8; ++j)
        xs[j * 512 + t] = X1[clampi(base + j * 512 + t, capX1)];
    __syncthreads();
    int kyidx = t >> 4, kx = t & 15;
    int ky = (kyidx < 16) ? kyidx : (224 + kyidx);
    float re = 0.f, im = 0.f;
    for (int y = 0; y < 256; ++y) {
        float2 v = xs[y * 16 + kx];
        float2 w = tw[(ky * y) & 255];
        re += v.x * w.x + v.y * w.y;   // v * e^{-i th}
        im += v.y * w.x - v.x * w.y;
    }
    Cft[clampi(blockIdx.x * 512u + t, capC)] = make_float2(re, im);
}

// ---- K3: mode mixing. block = mode (kyidx*16+kx). Outft[b,o] = sum_i Cft[b,i]*W[i,o]
__global__ __launch_bounds__(256) void k3_mix(const float2* __restrict__ Cft,
                                              const void* __restrict__ w1r, const void* __restrict__ w1i,
                                              const void* __restrict__ w2r, const void* __restrict__ w2i,
                                              float2* __restrict__ Outft,
                                              const int* __restrict__ flag,
                                              unsigned capC, unsigned capO) {
    __shared__ float2 wsm[4096];  // [i*64+o]
    __shared__ float2 cs[1024];   // [b*64+i]
    int t = threadIdx.x;
    int f32 = flag[0];
    int kyidx = blockIdx.x >> 4;
    int moff = ((kyidx < 16) ? kyidx : (kyidx - 16)) * 16 + (blockIdx.x & 15);
    const void* wr = (kyidx < 16) ? w1r : w2r;
    const void* wi = (kyidx < 16) ? w1i : w2i;
    for (int j = 0; j < 16; ++j) {
        int io = j * 256 + t;  // i*64+o
        wsm[io] = make_float2(ld_in(wr, (size_t)io * 256 + moff, f32),
                              ld_in(wi, (size_t)io * 256 + moff, f32));
    }
    for (int j = 0; j < 4; ++j) {
        int bi = j * 256 + t;
        cs[bi] = Cft[clampi((unsigned)bi * 512u + blockIdx.x, capC)];
    }
    __syncthreads();
    int o = t & 63, bq = t >> 6;
    for (int jb = 0; jb < 4; ++jb) {
        int b = bq * 4 + jb;
        float re = 0.f, im = 0.f;
        for (int i = 0; i < 64; ++i) {
            float2 c = cs[b * 64 + i];
            float2 w = wsm[i * 64 + o];
            re += c.x * w.x - c.y * w.y;
            im += c.x * w.y + c.y * w.x;
        }
        Outft[clampi((unsigned)(b * 64 + o) * 512u + blockIdx.x, capO)] = make_float2(re, im);
    }
}

// ---- K4: inverse DFT over y, fold 1/(H*W) and irfft alpha (2x for kx>0).
__global__ __launch_bounds__(256) void k4_idfty(const float2* __restrict__ Outft,
                                                float2* __restrict__ G1,
                                                unsigned capO, unsigned capG) {
    __shared__ float2 tw[256];
    __shared__ float2 fs[512];  // [kyidx][kx]
    int t = threadIdx.x;
    float sv, cv;
    sincosf(TWO_PI * (float)t * (1.0f / 256.0f), &sv, &cv);
    tw[t] = make_float2(cv, sv);
    unsigned base = blockIdx.x * 512u;
    fs[t] = Outft[clampi(base + t, capO)];
    fs[t + 256] = Outft[clampi(base + t + 256, capO)];
    __syncthreads();
    int kx = t & 15, y0 = t >> 4;
    float alpha = ((kx == 0) ? 1.0f : 2.0f) * (1.0f / 65536.0f);
    for (int jj = 0; jj < 16; ++jj) {
        int y = jj * 16 + y0;
        float re = 0.f, im = 0.f;
        for (int k = 0; k < 32; ++k) {
            int ky = (k < 16) ? k : (224 + k);
            float2 f = fs[k * 16 + kx];
            float2 w = tw[(ky * y) & 255];  // e^{+i th}
            re += f.x * w.x - f.y * w.y;
            im += f.x * w.y + f.y * w.x;
        }
        G1[clampi((blockIdx.x * 256u + y) * 16u + kx, capG)] = make_float2(re * alpha, im * alpha);
    }
}

// ---- K5: g = Re(idft_x(G1)); l = 3x3 circular conv + bias; out = g*l
// block = (tx,ty,b): 8x8 pixel tile, all 64 out-channels.
// thread t: og=t>>3 (o in {og,og+32}), pxg=t&7 -> rows 2*(pxg>>1)+{0,1}, cols 4*(pxg&1)+{0..3}
__global__ __launch_bounds__(256) void k5_final(const float2* __restrict__ G1, unsigned capG,
                                                const void* __restrict__ cin,
                                                const void* __restrict__ convw,
                                                const void* __restrict__ convb,
                                                const int* __restrict__ flag,
                                                void* __restrict__ out) {
    __shared__ float2 tw[256];
    __shared__ float2 g1s[16 * 8 * 17];  // [oc][yy][kx], stride 17
    __shared__ float xs[8][10][10];      // input tile, 8 in-ch, halo 1 (wrapped)
    __shared__ float wcs[64][8][9];      // conv weights [o][i_local][tap]
    int t = threadIdx.x;
    int f32 = flag[0];
    int tx = blockIdx.x, ty = blockIdx.y, bz = blockIdx.z;
    {
        float sv, cv;
        sincosf(TWO_PI * (float)t * (1.0f / 256.0f), &sv, &cv);
        tw[t] = make_float2(cv, sv);
    }
    int og = t >> 3, pxg = t & 7, rp = pxg >> 1, cq = pxg & 1;

    float g[2][8];
    for (int h = 0; h < 2; ++h)
        for (int j = 0; j < 8; ++j) g[h][j] = 0.f;

    // Phase A: inverse DFT over x, o staged in 4 chunks of 16
    for (int c4 = 0; c4 < 4; ++c4) {
        __syncthreads();
        for (int j = 0; j < 8; ++j) {
            int idx = j * 256 + t;               // 0..2047
            int oc = idx >> 7, rem = idx & 127;  // yy=rem>>4, kx=rem&15
            unsigned gi = ((unsigned)(bz * 64 + c4 * 16 + oc) * 256u + ty * 8u + (rem >> 4)) * 16u + (rem & 15);
            g1s[oc * 136 + (rem >> 4) * 17 + (rem & 15)] = G1[clampi(gi, capG)];
        }
        __syncthreads();
        for (int h = 0; h < 2; ++h) {
            int o = og + h * 32;
            if ((o >> 4) == c4) {
                int oc = o & 15;
                for (int j = 0; j < 8; ++j) {
                    int yy = 2 * rp + (j >> 2);
                    int xg = tx * 8 + 4 * cq + (j & 3);
                    float a = 0.f;
                    for (int kx = 0; kx < 16; ++kx) {
                        float2 f = g1s[oc * 136 + yy * 17 + kx];
                        float2 w = tw[(kx * xg) & 255];
                        a += f.x * w.x - f.y * w.y;  // Re(F * e^{+i th})
                    }
                    g[h][j] = a;
                }
            }
        }
    }

    // Phase B: 3x3 circular conv, in-channels staged 8 at a time
    float acc[2][8];
    for (int h = 0; h < 2; ++h)
        for (int j = 0; j < 8; ++j) acc[h][j] = 0.f;

    for (int ic = 0; ic < 8; ++ic) {
        __syncthreads();
        for (int j = t; j < 800; j += 256) {
            int i = j / 100, rem = j % 100;
            int yy = rem / 10, xx = rem % 10;
            int yg = (ty * 8 + yy - 1) & 255;
            int xg2 = (tx * 8 + xx - 1) & 255;
            xs[i][yy][xx] = ld_in(cin, ((size_t)(bz * 64 + ic * 8 + i) * 256 + yg) * 256 + xg2, f32);
        }
        for (int j = t; j < 4608; j += 256) {
            int oo = j / 72, rem = j % 72;
            wcs[oo][rem / 9][rem % 9] = ld_in(convw, (size_t)(oo * 64 + ic * 8 + rem / 9) * 9 + rem % 9, f32);
        }
        __syncthreads();
        for (int i = 0; i < 8; ++i) {
            float xr[4][6];
            for (int ry = 0; ry < 4; ++ry)
                for (int cx = 0; cx < 6; ++cx) xr[ry][cx] = xs[i][2 * rp + ry][4 * cq + cx];
            for (int h = 0; h < 2; ++h) {
                int o = og + h * 32;
                for (int k = 0; k < 9; ++k) {
                    float wv = wcs[o][i][k];
                    int dy = k / 3, dx = k % 3;
                    for (int j = 0; j < 8; ++j)
                        acc[h][j] = fmaf(wv, xr[(j >> 2) + dy][(j & 3) + dx], acc[h][j]);
                }
            }
        }
    }

    // Epilogue: out = g * (conv + bias); store dtype follows input dtype
    for (int h = 0; h < 2; ++h) {
        int o = og + h * 32;
        float bias = ld_in(convb, o, f32);
        for (int j = 0; j < 8; ++j) {
            int yy = 2 * rp + (j >> 2);
            size_t idx = (((size_t)bz * 64 + o) * 256 + ty * 8 + yy) * 256 + tx * 8 + 4 * cq + (j & 3);
            float val = g[h][j] * (acc[h][j] + bias);
            if (f32) ((float*)out)[idx] = val;
            else     ((bf16*)out)[idx] = __float2bfloat16(val);
        }
    }
}

extern "C" void kernel_launch(void* const* d_in, const int* in_sizes, int n_in,
                              void* d_out, int out_size, void* d_ws, size_t ws_size,
                              hipStream_t stream) {
    char* ws = (char*)d_ws;
    int* flag = (int*)ws;  // 1KB header
    const size_t offX1 = 1024;
    const size_t offC  = offX1 + 33554432;   // X1: 4,194,304 float2
    const size_t offO  = offC + 4194304;     // Cft: 524,288 float2
    // element capacities derived from actual ws_size (clamped accesses => finite results)
    unsigned capX1, capC, capO;
    {
        size_t a;
        a = (ws_size > offX1 + 8) ? (ws_size - offX1) / 8 : 1;
        capX1 = (unsigned)(a < 4194304 ? a : 4194304);
        a = (ws_size > offC + 8) ? (ws_size - offC) / 8 : 1;
        capC = (unsigned)(a < 524288 ? a : 524288);
        a = (ws_size > offO + 8) ? (ws_size - offO) / 8 : 1;
        capO = (unsigned)(a < 524288 ? a : 524288);
    }
    float2* X1    = (float2*)(ws + offX1);
    float2* Cft   = (float2*)(ws + offC);
    float2* Outft = (float2*)(ws + offO);
    float2* G1    = X1;  // reuse (X1 dead after k2)

    k_probe<<<1, 256, 0, stream>>>((const unsigned short*)d_in[0], flag);
    k1_dftx<<<16384, 256, 0, stream>>>(d_in[0], flag, X1, capX1);
    k2_dfty<<<1024, 512, 0, stream>>>(X1, Cft, capX1, capC);
    k3_mix<<<512, 256, 0, stream>>>(Cft, d_in[1], d_in[2], d_in[3], d_in[4],
                                    Outft, flag, capC, capO);
    k4_idfty<<<1024, 256, 0, stream>>>(Outft, G1, capO, capX1);
    dim3 g5(32, 32, 16);
    k5_final<<<g5, 256, 0, stream>>>(G1, capX1, d_in[0], d_in[5], d_in[6], flag, d_out);
}